// Round 7
// baseline (992.101 us; speedup 1.0000x reference)
//
#include <hip/hip_runtime.h>
#include <cstdint>
#include <cstddef>

typedef __attribute__((ext_vector_type(8))) short short8;     // 8 x 16-bit (4 VGPRs)
typedef __attribute__((ext_vector_type(8))) _Float16 f16x8;   // fp16 MFMA frag
typedef __attribute__((ext_vector_type(4))) float f32x4;
typedef __attribute__((ext_vector_type(4))) unsigned short u16x4;
typedef __attribute__((ext_vector_type(4))) unsigned int u32x4;
typedef unsigned short u16;

#define FP_  2048
#define AD_  1024
#define BB_  512
#define TT_  50000
#define BETA_ 0.125f

// ---------- fp32 -> bf16 (RNE) helpers ----------
__device__ __forceinline__ u16 f2bf(float x){
  uint32_t u = __builtin_bit_cast(uint32_t, x);
  u = (u + 0x7fffu + ((u >> 16) & 1u)) >> 16;
  return (u16)u;
}
__device__ __forceinline__ float bf2f(u16 h){
  uint32_t u = ((uint32_t)h) << 16;
  return __builtin_bit_cast(float, u);
}
__device__ __forceinline__ u16 f2h_bits(float x){
  _Float16 h = (_Float16)x;            // RNE
  return __builtin_bit_cast(u16, h);
}

// ---------- elementwise fp32 -> (hi,lo) bf16 ----------
__global__ void conv_hilo_k(const float* __restrict__ src, u16* __restrict__ hi,
                            u16* __restrict__ lo, int n){
  int i = (blockIdx.x * blockDim.x + threadIdx.x) * 4;
  if (i >= n) return;
  f32x4 v = *reinterpret_cast<const f32x4*>(src + i);
  u16x4 h, l;
  #pragma unroll
  for (int e = 0; e < 4; ++e){
    float x = v[e];
    u16 hs = f2bf(x);
    h[e] = hs;
    l[e] = f2bf(x - bf2f(hs));
  }
  *reinterpret_cast<u16x4*>(hi + i) = h;
  *reinterpret_cast<u16x4*>(lo + i) = l;
}

// ---------- W[R][C] -> out[C][R] with hi/lo split (LDS tile transpose) ----------
__global__ void conv_hilo_T_k(const float* __restrict__ W, u16* __restrict__ hiT,
                              u16* __restrict__ loT, int R, int C){
  __shared__ float tile[32][33];
  int c0 = blockIdx.x * 32;
  int r0 = blockIdx.y * 32;
  int tx = threadIdx.x;   // 0..31
  int ty = threadIdx.y;   // 0..7
  #pragma unroll
  for (int i = 0; i < 32; i += 8)
    tile[ty + i][tx] = W[(size_t)(r0 + ty + i) * C + c0 + tx];
  __syncthreads();
  #pragma unroll
  for (int i = 0; i < 32; i += 8){
    float x = tile[tx][ty + i];              // = W[r0+tx][c0+ty+i]
    u16 hs = f2bf(x);
    size_t o = (size_t)(c0 + ty + i) * R + r0 + tx;   // out[f][a]
    hiT[o] = hs;
    loT[o] = f2bf(x - bf2f(hs));
  }
}

// ---------- c[b] = dot(Xi[b,:], b_temp) : one wave per row ----------
__global__ void dot_rows_k(const float* __restrict__ Xi, const float* __restrict__ bt,
                           float* __restrict__ c, int K){
  int row  = blockIdx.x * 4 + (threadIdx.x >> 6);
  int lane = threadIdx.x & 63;
  float s = 0.f;
  for (int a = lane; a < K; a += 64) s += Xi[(size_t)row * K + a] * bt[a];
  #pragma unroll
  for (int off = 32; off; off >>= 1) s += __shfl_down(s, off);
  if (lane == 0) c[row] = s;
}

// ---------- split-bf16 small GEMM: C = A·B^T + colBias (3-term hi/lo) ----------
// OUT16: 0=none, 1=bf16 hi/lo pair, 2=fp16 hi/lo pair
template<int TM, int TN, int FM, int FN, int OUT16>
__global__ __launch_bounds__(256, 2)
void gemm_hilo(const u16* __restrict__ Ahi, const u16* __restrict__ Alo,
               const u16* __restrict__ Bhi, const u16* __restrict__ Blo,
               int M, int N, int K,
               float* __restrict__ Cf, u16* __restrict__ Chi, u16* __restrict__ Clo,
               const float* __restrict__ colBias)
{
  constexpr int BK = 32;
  constexpr int WM = TM / (16 * FM);
  constexpr int WN = TN / (16 * FN);
  static_assert(WM * WN == 4, "4 waves / 256 threads");
  constexpr int BUFE = (2 * TM + 2 * TN) * BK;

  __shared__ __align__(16) u16 lds[2 * BUFE];

  const int m0 = blockIdx.x * TM;
  const int n0 = blockIdx.y * TN;

  const int tid  = threadIdx.x;
  const int w    = tid >> 6;
  const int lane = tid & 63;
  const int lr   = lane & 15;
  const int lg   = lane >> 4;
  const int wm   = w / WN;
  const int wn   = w % WN;

  const int rrA = tid >> 2;     // 0..63
  const int chA = tid & 3;      // 16B chunk

  short8 ra[2], rb[2];

  f32x4 acc[FM][FN];
  #pragma unroll
  for (int i = 0; i < FM; ++i)
    #pragma unroll
    for (int j = 0; j < FN; ++j)
      acc[i][j] = (f32x4){0.f, 0.f, 0.f, 0.f};

  auto stage_load = [&](int k0){
    int gm = m0 + rrA;
    ra[0] = *reinterpret_cast<const short8*>(Ahi + (size_t)gm * K + k0 + chA * 8);
    ra[1] = *reinterpret_cast<const short8*>(Alo + (size_t)gm * K + k0 + chA * 8);
    int gn = n0 + rrA; if (gn > N - 1) gn = N - 1;
    rb[0] = *reinterpret_cast<const short8*>(Bhi + (size_t)gn * K + k0 + chA * 8);
    rb[1] = *reinterpret_cast<const short8*>(Blo + (size_t)gn * K + k0 + chA * 8);
  };
  auto stage_store = [&](int buf){
    u16* As_hi = lds + buf * BUFE;
    u16* As_lo = As_hi + TM * BK;
    u16* Bs_hi = As_hi + 2 * TM * BK;
    u16* Bs_lo = As_hi + 2 * TM * BK + TN * BK;
    int row = rrA;
    int sw  = (chA ^ ((row >> 1) & 3)) << 3;
    *reinterpret_cast<short8*>(As_hi + row * BK + sw) = ra[0];
    *reinterpret_cast<short8*>(As_lo + row * BK + sw) = ra[1];
    *reinterpret_cast<short8*>(Bs_hi + row * BK + sw) = rb[0];
    *reinterpret_cast<short8*>(Bs_lo + row * BK + sw) = rb[1];
  };

  const int NT = K / BK;
  stage_load(0);
  stage_store(0);
  __syncthreads();

  int cur = 0;
  for (int t = 0; t < NT; ++t){
    const bool have_next = (t + 1 < NT);
    if (have_next) stage_load((t + 1) * BK);

    u16* As_hi = lds + cur * BUFE;
    u16* As_lo = As_hi + TM * BK;
    u16* Bs_hi = As_hi + 2 * TM * BK;
    u16* Bs_lo = As_hi + 2 * TM * BK + TN * BK;

    short8 ah[FM], al[FM], bh[FN], bl[FN];
    #pragma unroll
    for (int i = 0; i < FM; ++i){
      int row = wm * FM * 16 + i * 16 + lr;
      int off = row * BK + ((lg ^ ((row >> 1) & 3)) << 3);
      ah[i] = *reinterpret_cast<short8*>(As_hi + off);
      al[i] = *reinterpret_cast<short8*>(As_lo + off);
    }
    #pragma unroll
    for (int j = 0; j < FN; ++j){
      int row = wn * FN * 16 + j * 16 + lr;
      int off = row * BK + ((lg ^ ((row >> 1) & 3)) << 3);
      bh[j] = *reinterpret_cast<short8*>(Bs_hi + off);
      bl[j] = *reinterpret_cast<short8*>(Bs_lo + off);
    }
    #pragma unroll
    for (int i = 0; i < FM; ++i)
      #pragma unroll
      for (int j = 0; j < FN; ++j){
        acc[i][j] = __builtin_amdgcn_mfma_f32_16x16x32_bf16(ah[i], bh[j], acc[i][j], 0, 0, 0);
        acc[i][j] = __builtin_amdgcn_mfma_f32_16x16x32_bf16(ah[i], bl[j], acc[i][j], 0, 0, 0);
        acc[i][j] = __builtin_amdgcn_mfma_f32_16x16x32_bf16(al[i], bh[j], acc[i][j], 0, 0, 0);
      }

    if (have_next){
      __builtin_amdgcn_sched_barrier(0);
      stage_store(cur ^ 1);
      __syncthreads();
    }
    cur ^= 1;
  }

  #pragma unroll
  for (int i = 0; i < FM; ++i){
    int rbase = m0 + wm * FM * 16 + i * 16 + lg * 4;
    #pragma unroll
    for (int j = 0; j < FN; ++j){
      int gcol = n0 + wn * FN * 16 + j * 16 + lr;
      if (gcol < N){
        float cb = colBias ? colBias[gcol] : 0.f;
        #pragma unroll
        for (int r = 0; r < 4; ++r){
          int grow = rbase + r;
          float v = acc[i][j][r] + cb;
          size_t idx = (size_t)grow * N + gcol;
          if (Cf) Cf[idx] = v;
          if constexpr (OUT16 == 1){
            u16 hs = f2bf(v);
            Chi[idx] = hs;
            Clo[idx] = f2bf(v - bf2f(hs));
          } else if constexpr (OUT16 == 2){
            _Float16 h = (_Float16)v;
            Chi[idx] = __builtin_bit_cast(u16, h);
            Clo[idx] = f2h_bits(v - (float)h);
          }
        }
      }
    }
  }
}

// ---------- BIG GEMM: LDS-free, barrier-free direct-fragment dataflow ----------
// out = alpha*(A·B^T + rowAdd). A = Y fp16 [512][2048] (L2-resident), B = fp32
// templates (HBM stream) loaded DIRECTLY into each lane's MFMA fragment
// (row = n-index per lane, 8 consecutive k per lane) and converted in-register
// via v_cvt_pkrtz_f16_f32. No LDS, no __syncthreads, no vmcnt choreography:
// even/odd register double-buffer, loads for step t+2 issued right after
// step t consumes its set; compiler-inserted waitcnt. 4 waves/block (64x128
// block tile, 32x64 wave tile), fully independent waves.
__global__ __launch_bounds__(256, 3)
void gemm_big(const u16* __restrict__ Ah,      // fp16 bits [512][2048]
              const float* __restrict__ Bf,    // [50000][2048]
              float* __restrict__ C,
              const float* __restrict__ rowAdd, float alpha)
{
  constexpr int TM = 64, TN = 128, BK = 32;
  constexpr int K = FP_, NN = TT_;
  constexpr int NT = K / BK;                 // 64

  // bijective XCD grouping: xcd<7 own 49 N-strips, xcd=7 owns 48 (391 total).
  // g = s*8 + mt -> the 8 M-blocks of a strip run concurrently on one XCD
  // (B-strip fetched ~once into that XCD's L2; FETCH 250MB<410MB confirms).
  int id  = blockIdx.x;
  int xcd = id & 7;
  int g   = id >> 3;
  int mt  = g & 7;            // 8 M-tiles of 64
  int s   = g >> 3;           // 0..48
  int strips = (xcd < 7) ? 49 : 48;
  if (s >= strips) return;
  int nt = ((xcd < 7) ? xcd * 49 : 343) + s;   // 0..390
  const int m0 = mt * TM;
  const int n0 = nt * TN;

  const int tid  = threadIdx.x;
  const int w    = tid >> 6;        // 0..3
  const int lane = tid & 63;
  const int lr   = lane & 15;
  const int lg   = lane >> 4;
  const int wm   = w >> 1;          // 0..1  (32-row band)
  const int wn   = w & 1;           // 0..1  (64-col band)

  // per-lane fragment base pointers (fixed rows; k advances by BK per step)
  const u16* ap[2];
  #pragma unroll
  for (int i = 0; i < 2; ++i)
    ap[i] = Ah + (size_t)(m0 + wm * 32 + i * 16 + lr) * K + lg * 8;
  const float* bp[4];
  #pragma unroll
  for (int j = 0; j < 4; ++j){
    int r = n0 + wn * 64 + j * 16 + lr;
    if (r > NN - 1) r = NN - 1;     // tail clamp; OOB cols discarded at epilogue
    bp[j] = Bf + (size_t)r * K + lg * 8;
  }

  f32x4 acc[2][4];
  #pragma unroll
  for (int i = 0; i < 2; ++i)
    #pragma unroll
    for (int j = 0; j < 4; ++j)
      acc[i][j] = (f32x4){0.f, 0.f, 0.f, 0.f};

  f32x4  bE[4][2], bO[4][2];        // fp32 fragments in flight (named sets)
  short8 aE[2],    aO[2];           // fp16 fragments in flight

  auto loadB = [&](int t, f32x4 (&bb)[4][2]){
    #pragma unroll
    for (int j = 0; j < 4; ++j){
      bb[j][0] = *reinterpret_cast<const f32x4*>(bp[j] + t * BK);
      bb[j][1] = *reinterpret_cast<const f32x4*>(bp[j] + t * BK + 4);
    }
  };
  auto loadA = [&](int t, short8 (&aa)[2]){
    #pragma unroll
    for (int i = 0; i < 2; ++i)
      aa[i] = *reinterpret_cast<const short8*>(ap[i] + t * BK);
  };
  auto pack8 = [](const f32x4& lo, const f32x4& hi) -> f16x8 {
    u32x4 u;
    u[0] = __builtin_bit_cast(unsigned int, __builtin_amdgcn_cvt_pkrtz(lo[0], lo[1]));
    u[1] = __builtin_bit_cast(unsigned int, __builtin_amdgcn_cvt_pkrtz(lo[2], lo[3]));
    u[2] = __builtin_bit_cast(unsigned int, __builtin_amdgcn_cvt_pkrtz(hi[0], hi[1]));
    u[3] = __builtin_bit_cast(unsigned int, __builtin_amdgcn_cvt_pkrtz(hi[2], hi[3]));
    return __builtin_bit_cast(f16x8, u);
  };
  auto step = [&](f32x4 (&bb)[4][2], short8 (&aa)[2]){
    f16x8 bh[4];
    #pragma unroll
    for (int j = 0; j < 4; ++j) bh[j] = pack8(bb[j][0], bb[j][1]);   // waits B set
    #pragma unroll
    for (int i = 0; i < 2; ++i){
      f16x8 ah = __builtin_bit_cast(f16x8, aa[i]);                   // waits A set
      #pragma unroll
      for (int j = 0; j < 4; ++j)
        acc[i][j] = __builtin_amdgcn_mfma_f32_16x16x32_f16(ah, bh[j], acc[i][j], 0, 0, 0);
    }
  };

  // prologue: two sets in flight
  loadB(0, bE); loadA(0, aE);
  loadB(1, bO); loadA(1, aO);

  for (int t = 0; t < NT; t += 2){
    step(bE, aE);                                   // consume t
    if (t + 2 < NT){ loadB(t + 2, bE); loadA(t + 2, aE); }   // refill for t+2
    step(bO, aO);                                   // consume t+1
    if (t + 3 < NT){ loadB(t + 3, bO); loadA(t + 3, aO); }   // refill for t+3
  }

  // ---- epilogue: row=(lane>>4)*4+reg (A index), col=lane&15 (B index) ----
  #pragma unroll
  for (int i = 0; i < 2; ++i){
    int rbase = m0 + wm * 32 + i * 16 + lg * 4;
    #pragma unroll
    for (int j = 0; j < 4; ++j){
      int gcol = n0 + wn * 64 + j * 16 + lr;
      if (gcol < NN){
        #pragma unroll
        for (int r = 0; r < 4; ++r){
          int grow = rbase + r;
          float v = (acc[i][j][r] + rowAdd[grow]) * alpha;
          C[(size_t)grow * NN + gcol] = v;
        }
      }
    }
  }
}

extern "C" void kernel_launch(void* const* d_in, const int* in_sizes, int n_in,
                              void* d_out, int out_size, void* d_ws, size_t ws_size,
                              hipStream_t stream){
  (void)in_sizes; (void)n_in; (void)out_size; (void)ws_size;
  const float* m    = (const float*)d_in[0];   // [512][2048]
  const float* tpl  = (const float*)d_in[1];   // [50000][2048]
  const float* Wmol = (const float*)d_in[2];   // [1024][2048]
  const float* bmol = (const float*)d_in[3];   // [1024]
  const float* Wtmp = (const float*)d_in[4];   // [1024][2048]
  const float* btmp = (const float*)d_in[5];   // [1024]
  float* out = (float*)d_out;                  // [512][50000]

  uint8_t* wp = (uint8_t*)d_ws;
  auto carve = [&](size_t bytes) -> void* {
    void* p = (void*)wp;
    wp += (bytes + 255) & ~(size_t)255;
    return p;
  };
  u16* m_hi   = (u16*)carve((size_t)BB_ * FP_ * 2);
  u16* m_lo   = (u16*)carve((size_t)BB_ * FP_ * 2);
  u16* wm_hi  = (u16*)carve((size_t)AD_ * FP_ * 2);
  u16* wm_lo  = (u16*)carve((size_t)AD_ * FP_ * 2);
  u16* wtT_hi = (u16*)carve((size_t)FP_ * AD_ * 2);
  u16* wtT_lo = (u16*)carve((size_t)FP_ * AD_ * 2);
  float* Xi   = (float*)carve((size_t)BB_ * AD_ * 4);
  u16* Xi_hi  = (u16*)carve((size_t)BB_ * AD_ * 2);
  u16* Xi_lo  = (u16*)carve((size_t)BB_ * AD_ * 2);
  u16* Y_hi   = (u16*)carve((size_t)BB_ * FP_ * 2);   // fp16 bits
  u16* Y_lo   = (u16*)carve((size_t)BB_ * FP_ * 2);   // fp16 bits (unused by big gemm)
  float* cvec = (float*)carve((size_t)BB_ * 4);

  // 1) split inputs to bf16 hi/lo (W_temp also transposed to [FP][A])
  conv_hilo_k<<<(BB_ * FP_ / 4 + 255) / 256, 256, 0, stream>>>(m, m_hi, m_lo, BB_ * FP_);
  conv_hilo_k<<<(AD_ * FP_ / 4 + 255) / 256, 256, 0, stream>>>(Wmol, wm_hi, wm_lo, AD_ * FP_);
  conv_hilo_T_k<<<dim3(FP_ / 32, AD_ / 32), dim3(32, 8), 0, stream>>>(Wtmp, wtT_hi, wtT_lo, AD_, FP_);

  // 2) Xi = m @ W_mol^T + b_mol   [512 x 1024], K=2048  (fp32 + bf16 hi/lo out)
  gemm_hilo<64, 64, 2, 2, 1><<<dim3(BB_ / 64, AD_ / 64), 256, 0, stream>>>(
      m_hi, m_lo, wm_hi, wm_lo, BB_, AD_, FP_,
      Xi, Xi_hi, Xi_lo, bmol);

  // 3) c[b] = Xi[b,:] . b_temp
  dot_rows_k<<<BB_ / 4, 256, 0, stream>>>(Xi, btmp, cvec, AD_);

  // 4) Y = Xi @ W_temp   [512 x 2048], K=1024  -> fp16 hi/lo (big gemm uses hi only)
  gemm_hilo<64, 64, 2, 2, 2><<<dim3(BB_ / 64, FP_ / 64), 256, 0, stream>>>(
      Xi_hi, Xi_lo, wtT_hi, wtT_lo, BB_, FP_, AD_,
      nullptr, Y_hi, Y_lo, nullptr);

  // 5) out = BETA * (Y @ templates^T + c)   [512 x 50000], K=2048
  //    3136 blocks = 8 XCD x 49 strip-slots x 8 M-tiles; 8 masked.
  gemm_big<<<3136, 256, 0, stream>>>(Y_hi, tpl, out, cvec, BETA_);
}

// Round 9
// 417.881 us; speedup vs baseline: 2.3741x; 2.3741x over previous
//
#include <hip/hip_runtime.h>
#include <cstdint>
#include <cstddef>

typedef __attribute__((ext_vector_type(8))) short short8;     // 8 x 16-bit (4 VGPRs)
typedef __attribute__((ext_vector_type(8))) _Float16 f16x8;   // fp16 MFMA frag
typedef __attribute__((ext_vector_type(4))) float f32x4;
typedef __attribute__((ext_vector_type(16))) float f32x16;    // 32x32 MFMA acc
typedef __attribute__((ext_vector_type(4))) unsigned short u16x4;
typedef unsigned short u16;

#define FP_  2048
#define AD_  1024
#define BB_  512
#define TT_  50000
#define BETA_ 0.125f

// ---------- fp32 -> bf16 (RNE) helpers ----------
__device__ __forceinline__ u16 f2bf(float x){
  uint32_t u = __builtin_bit_cast(uint32_t, x);
  u = (u + 0x7fffu + ((u >> 16) & 1u)) >> 16;
  return (u16)u;
}
__device__ __forceinline__ float bf2f(u16 h){
  uint32_t u = ((uint32_t)h) << 16;
  return __builtin_bit_cast(float, u);
}
__device__ __forceinline__ u16 f2h_bits(float x){
  _Float16 h = (_Float16)x;            // RNE
  return __builtin_bit_cast(u16, h);
}
__device__ __forceinline__ unsigned int pkrtz_u32(float a, float b){
  return __builtin_bit_cast(unsigned int, __builtin_amdgcn_cvt_pkrtz(a, b));
}

// ---------- async global->LDS, 16B per lane ----------
__device__ __forceinline__ void gload_lds16(const void* g, void* l){
  __builtin_amdgcn_global_load_lds((const __attribute__((address_space(1))) void*)g,
                                   (__attribute__((address_space(3))) void*)l,
                                   16, 0, 0);
}

#define SB   __builtin_amdgcn_s_barrier()
#define SCH  __builtin_amdgcn_sched_barrier(0)
#define WAIT_LGKM0 asm volatile("s_waitcnt lgkmcnt(0)" ::: "memory")
#define WAIT_VM(n) asm volatile("s_waitcnt vmcnt(" #n ")" ::: "memory")

// ---------- elementwise fp32 -> (hi,lo) bf16 ----------
__global__ void conv_hilo_k(const float* __restrict__ src, u16* __restrict__ hi,
                            u16* __restrict__ lo, int n){
  int i = (blockIdx.x * blockDim.x + threadIdx.x) * 4;
  if (i >= n) return;
  f32x4 v = *reinterpret_cast<const f32x4*>(src + i);
  u16x4 h, l;
  #pragma unroll
  for (int e = 0; e < 4; ++e){
    float x = v[e];
    u16 hs = f2bf(x);
    h[e] = hs;
    l[e] = f2bf(x - bf2f(hs));
  }
  *reinterpret_cast<u16x4*>(hi + i) = h;
  *reinterpret_cast<u16x4*>(lo + i) = l;
}

// ---------- W[R][C] -> out[C][R] with hi/lo split (LDS tile transpose) ----------
__global__ void conv_hilo_T_k(const float* __restrict__ W, u16* __restrict__ hiT,
                              u16* __restrict__ loT, int R, int C){
  __shared__ float tile[32][33];
  int c0 = blockIdx.x * 32;
  int r0 = blockIdx.y * 32;
  int tx = threadIdx.x;   // 0..31
  int ty = threadIdx.y;   // 0..7
  #pragma unroll
  for (int i = 0; i < 32; i += 8)
    tile[ty + i][tx] = W[(size_t)(r0 + ty + i) * C + c0 + tx];
  __syncthreads();
  #pragma unroll
  for (int i = 0; i < 32; i += 8){
    float x = tile[tx][ty + i];              // = W[r0+tx][c0+ty+i]
    u16 hs = f2bf(x);
    size_t o = (size_t)(c0 + ty + i) * R + r0 + tx;   // out[f][a]
    hiT[o] = hs;
    loT[o] = f2bf(x - bf2f(hs));
  }
}

// ---------- c[b] = dot(Xi[b,:], b_temp) : one wave per row ----------
__global__ void dot_rows_k(const float* __restrict__ Xi, const float* __restrict__ bt,
                           float* __restrict__ c, int K){
  int row  = blockIdx.x * 4 + (threadIdx.x >> 6);
  int lane = threadIdx.x & 63;
  float s = 0.f;
  for (int a = lane; a < K; a += 64) s += Xi[(size_t)row * K + a] * bt[a];
  #pragma unroll
  for (int off = 32; off; off >>= 1) s += __shfl_down(s, off);
  if (lane == 0) c[row] = s;
}

// ---------- split-bf16 small GEMM: C = A·B^T + colBias (3-term hi/lo) ----------
// OUT16: 0=none, 1=bf16 hi/lo pair, 2=fp16 hi/lo pair
template<int TM, int TN, int FM, int FN, int OUT16>
__global__ __launch_bounds__(256, 2)
void gemm_hilo(const u16* __restrict__ Ahi, const u16* __restrict__ Alo,
               const u16* __restrict__ Bhi, const u16* __restrict__ Blo,
               int M, int N, int K,
               float* __restrict__ Cf, u16* __restrict__ Chi, u16* __restrict__ Clo,
               const float* __restrict__ colBias)
{
  constexpr int BK = 32;
  constexpr int WM = TM / (16 * FM);
  constexpr int WN = TN / (16 * FN);
  static_assert(WM * WN == 4, "4 waves / 256 threads");
  constexpr int BUFE = (2 * TM + 2 * TN) * BK;

  __shared__ __align__(16) u16 lds[2 * BUFE];

  const int m0 = blockIdx.x * TM;
  const int n0 = blockIdx.y * TN;

  const int tid  = threadIdx.x;
  const int w    = tid >> 6;
  const int lane = tid & 63;
  const int lr   = lane & 15;
  const int lg   = lane >> 4;
  const int wm   = w / WN;
  const int wn   = w % WN;

  const int rrA = tid >> 2;     // 0..63
  const int chA = tid & 3;      // 16B chunk

  short8 ra[2], rb[2];

  f32x4 acc[FM][FN];
  #pragma unroll
  for (int i = 0; i < FM; ++i)
    #pragma unroll
    for (int j = 0; j < FN; ++j)
      acc[i][j] = (f32x4){0.f, 0.f, 0.f, 0.f};

  auto stage_load = [&](int k0){
    int gm = m0 + rrA;
    ra[0] = *reinterpret_cast<const short8*>(Ahi + (size_t)gm * K + k0 + chA * 8);
    ra[1] = *reinterpret_cast<const short8*>(Alo + (size_t)gm * K + k0 + chA * 8);
    int gn = n0 + rrA; if (gn > N - 1) gn = N - 1;
    rb[0] = *reinterpret_cast<const short8*>(Bhi + (size_t)gn * K + k0 + chA * 8);
    rb[1] = *reinterpret_cast<const short8*>(Blo + (size_t)gn * K + k0 + chA * 8);
  };
  auto stage_store = [&](int buf){
    u16* As_hi = lds + buf * BUFE;
    u16* As_lo = As_hi + TM * BK;
    u16* Bs_hi = As_hi + 2 * TM * BK;
    u16* Bs_lo = As_hi + 2 * TM * BK + TN * BK;
    int row = rrA;
    int sw  = (chA ^ ((row >> 1) & 3)) << 3;
    *reinterpret_cast<short8*>(As_hi + row * BK + sw) = ra[0];
    *reinterpret_cast<short8*>(As_lo + row * BK + sw) = ra[1];
    *reinterpret_cast<short8*>(Bs_hi + row * BK + sw) = rb[0];
    *reinterpret_cast<short8*>(Bs_lo + row * BK + sw) = rb[1];
  };

  const int NT = K / BK;
  stage_load(0);
  stage_store(0);
  __syncthreads();

  int cur = 0;
  for (int t = 0; t < NT; ++t){
    const bool have_next = (t + 1 < NT);
    if (have_next) stage_load((t + 1) * BK);

    u16* As_hi = lds + cur * BUFE;
    u16* As_lo = As_hi + TM * BK;
    u16* Bs_hi = As_hi + 2 * TM * BK;
    u16* Bs_lo = As_hi + 2 * TM * BK + TN * BK;

    short8 ah[FM], al[FM], bh[FN], bl[FN];
    #pragma unroll
    for (int i = 0; i < FM; ++i){
      int row = wm * FM * 16 + i * 16 + lr;
      int off = row * BK + ((lg ^ ((row >> 1) & 3)) << 3);
      ah[i] = *reinterpret_cast<short8*>(As_hi + off);
      al[i] = *reinterpret_cast<short8*>(As_lo + off);
    }
    #pragma unroll
    for (int j = 0; j < FN; ++j){
      int row = wn * FN * 16 + j * 16 + lr;
      int off = row * BK + ((lg ^ ((row >> 1) & 3)) << 3);
      bh[j] = *reinterpret_cast<short8*>(Bs_hi + off);
      bl[j] = *reinterpret_cast<short8*>(Bs_lo + off);
    }
    #pragma unroll
    for (int i = 0; i < FM; ++i)
      #pragma unroll
      for (int j = 0; j < FN; ++j){
        acc[i][j] = __builtin_amdgcn_mfma_f32_16x16x32_bf16(ah[i], bh[j], acc[i][j], 0, 0, 0);
        acc[i][j] = __builtin_amdgcn_mfma_f32_16x16x32_bf16(ah[i], bl[j], acc[i][j], 0, 0, 0);
        acc[i][j] = __builtin_amdgcn_mfma_f32_16x16x32_bf16(al[i], bh[j], acc[i][j], 0, 0, 0);
      }

    if (have_next){
      __builtin_amdgcn_sched_barrier(0);
      stage_store(cur ^ 1);
      __syncthreads();
    }
    cur ^= 1;
  }

  #pragma unroll
  for (int i = 0; i < FM; ++i){
    int rbase = m0 + wm * FM * 16 + i * 16 + lg * 4;
    #pragma unroll
    for (int j = 0; j < FN; ++j){
      int gcol = n0 + wn * FN * 16 + j * 16 + lr;
      if (gcol < N){
        float cb = colBias ? colBias[gcol] : 0.f;
        #pragma unroll
        for (int r = 0; r < 4; ++r){
          int grow = rbase + r;
          float v = acc[i][j][r] + cb;
          size_t idx = (size_t)grow * N + gcol;
          if (Cf) Cf[idx] = v;
          if constexpr (OUT16 == 1){
            u16 hs = f2bf(v);
            Chi[idx] = hs;
            Clo[idx] = f2bf(v - bf2f(hs));
          } else if constexpr (OUT16 == 2){
            _Float16 h = (_Float16)v;
            Chi[idx] = __builtin_bit_cast(u16, h);
            Clo[idx] = f2h_bits(v - (float)h);
          }
        }
      }
    }
  }
}

// ---------- BIG GEMM: 32x32x16 MFMA, high arithmetic-intensity LDS schedule ----------
// out = alpha*(A·B^T + rowAdd). A = Y fp16 [512][2048] (L2-resident), B = fp32
// templates -> fp16 (cvt_pkrtz) in staging. Block = 128 thr (2 waves),
// tile 128x128, wave tile 64x128 (FM=2, FN=4 of 32x32), BK=32.
// LDS 2 x (A 8KB + B 8KB) = 32KB -> 4 blocks/CU. AI = 42.7 FLOP/LDS-byte
// (vs 21 for the 16x16 config): LDS (~1250cy) ~ MFMA (~1030cy) per CU round.
// Ledger per wave per iter: issue A(t+1):4 gload_lds, [SCH], B(t+2):8 loads.
// Entering iter t: [B(t+1):8]. Post-MFMA: vmcnt(12) -> B(t+1) in regs;
// writeB; vmcnt(8) -> A(t+1) landed; lgkm0; s_barrier. Tail: 4/0.
__global__ __launch_bounds__(128, 2)
void gemm_big(const u16* __restrict__ Ah,      // fp16 bits [512][2048]
              const float* __restrict__ Bf,    // [50000][2048]
              float* __restrict__ C,
              const float* __restrict__ rowAdd, float alpha)
{
  constexpr int TMB = 128, TNB = 128, BK = 32;
  constexpr int K = FP_, NN = TT_;
  constexpr int NT = K / BK;                   // 64
  constexpr int SLOT_A = TMB * BK;             // 4096 u16 = 8KB
  constexpr int BUFE   = SLOT_A + TNB * BK;    // 8192 u16 = 16KB

  __shared__ __align__(16) u16 lds[2 * BUFE];  // 32KB

  // bijective XCD grouping: xcd<7 own 49 N-strips(128), xcd=7 owns 48 (391).
  // g = s*4 + mt -> 4 M-blocks of a strip concurrent on one XCD.
  int id  = blockIdx.x;
  int xcd = id & 7;
  int g   = id >> 3;          // 0..195
  int mt  = g & 3;
  int s   = g >> 2;           // 0..48
  int strips = (xcd < 7) ? 49 : 48;
  if (s >= strips) return;
  int nt = ((xcd < 7) ? xcd * 49 : 343) + s;   // 0..390
  const int m0 = mt * TMB;
  const int n0 = nt * TNB;

  const int tid  = threadIdx.x;     // 0..127
  const int w    = tid >> 6;        // 0..1
  const int lane = tid & 63;
  const int l31  = lane & 31;
  const int lhi  = lane >> 5;       // 0..1 (k-half selector)

  const int rowB = tid >> 3;        // 0..15 (+16p)
  const int c4   = tid & 7;         // f32x4 chunk of a 128B fp32 row-piece

  auto swz = [](int row, int ch){ return ch ^ ((row >> 1) & 3); };

  // ---- A: 4 gload_lds per wave per iter (16 rows of 64B per instr) ----
  auto issueA = [&](int t, u16* buf){
    int rl = lane >> 2;             // 0..15
    int cc = lane & 3;
    #pragma unroll
    for (int q = 0; q < 4; ++q){
      int row = w * 64 + q * 16 + rl;
      int sc  = swz(row, cc);                       // inverse swizzle on source
      const u16* gsrc = Ah + (size_t)(m0 + row) * K + t * BK + sc * 8;
      gload_lds16(gsrc, buf + (w * 64 + q * 16) * BK);   // linear dest
    }
  };
  // ---- B: 8 coalesced f32x4 loads per lane (8 lanes/row x 128B) ----
  auto issueB = [&](int t, f32x4 (&rb)[8]){
    #pragma unroll
    for (int p = 0; p < 8; ++p){
      int gn = n0 + rowB + p * 16; if (gn > NN - 1) gn = NN - 1;
      rb[p] = *reinterpret_cast<const f32x4*>(Bf + (size_t)gn * K + t * BK + c4 * 4);
    }
  };
  auto writeB = [&](u16* buf, f32x4 (&rb)[8]){
    u16* bb = buf + SLOT_A;
    #pragma unroll
    for (int p = 0; p < 8; ++p){
      int row = rowB + p * 16;
      uint2 hv;
      hv.x = pkrtz_u32(rb[p][0], rb[p][1]);
      hv.y = pkrtz_u32(rb[p][2], rb[p][3]);
      int gr = swz(row, c4 >> 1);
      *reinterpret_cast<uint2*>(bb + row * BK + gr * 8 + (c4 & 1) * 4) = hv;
    }
  };

  f32x16 acc[2][4];
  #pragma unroll
  for (int i = 0; i < 2; ++i)
    #pragma unroll
    for (int j = 0; j < 4; ++j)
      acc[i][j] = (f32x16){0.f,0.f,0.f,0.f,0.f,0.f,0.f,0.f,
                           0.f,0.f,0.f,0.f,0.f,0.f,0.f,0.f};

  // frag reads (32x32x16: lane holds row l31, k = lhi*8 + e within 16-k step)
  auto fragA = [&](u16* buf, int ks, int i) -> f16x8 {
    int row = w * 64 + i * 32 + l31;
    int ch  = ks * 2 + lhi;
    return __builtin_bit_cast(f16x8,
      *reinterpret_cast<short8*>(buf + row * BK + swz(row, ch) * 8));
  };
  auto fragB = [&](u16* buf, int ks, int j) -> f16x8 {
    int row = j * 32 + l31;
    int ch  = ks * 2 + lhi;
    return __builtin_bit_cast(f16x8,
      *reinterpret_cast<short8*>(buf + SLOT_A + row * BK + swz(row, ch) * 8));
  };

  f32x4 rbE[8], rbO[8];

  // ---- prologue: A(0)->buf0, B(0)->rbE, B(1)->rbO; publish tile 0 ----
  issueA(0, lds);                 // 4
  SCH;                            // pin A before B in the vmcnt queue
  issueB(0, rbE);                 // 8
  issueB(1, rbO);                 // 8      queue: [A0:4, B0:8, B1:8] = 20
  WAIT_VM(8);                     // A0 + B0 retired (B1:8 remain)
  writeB(lds, rbE);
  WAIT_LGKM0;
  SB; SCH;

  // ---- body ----
  auto body = [&](int t, f32x4 (&rbFill)[8], f32x4 (&rbPub)[8]){
    u16* sp  = lds + (t & 1) * BUFE;
    u16* spn = lds + ((t + 1) & 1) * BUFE;
    if (t + 1 < NT) issueA(t + 1, spn);     // 4 (into buffer freed at last bar)
    SCH;                                    // A strictly older than B(t+2)
    if (t + 2 < NT) issueB(t + 2, rbFill);  // 8

    #pragma unroll
    for (int ks = 0; ks < 2; ++ks){
      f16x8 a0 = fragA(sp, ks, 0), a1 = fragA(sp, ks, 1);
      #pragma unroll
      for (int j = 0; j < 4; ++j){
        f16x8 bj = fragB(sp, ks, j);
        acc[0][j] = __builtin_amdgcn_mfma_f32_32x32x16_f16(a0, bj, acc[0][j], 0, 0, 0);
        acc[1][j] = __builtin_amdgcn_mfma_f32_32x32x16_f16(a1, bj, acc[1][j], 0, 0, 0);
      }
    }
    SCH;

    if (t + 1 < NT){
      if (t + 2 < NT) { WAIT_VM(12); } else { WAIT_VM(4); }  // B(t+1) in regs
      writeB(spn, rbPub);
      if (t + 2 < NT) { WAIT_VM(8); } else { WAIT_VM(0); }   // A(t+1) landed
      WAIT_LGKM0;
      SB; SCH;
    }
  };

  for (int tt = 0; tt < NT; tt += 2){
    body(tt,     rbE, rbO);
    body(tt + 1, rbO, rbE);
  }

  // ---- epilogue: 32x32 C/D: col=lane&31, row=(reg&3)+8*(reg>>2)+4*(lane>>5) ----
  #pragma unroll
  for (int i = 0; i < 2; ++i){
    #pragma unroll
    for (int j = 0; j < 4; ++j){
      int gcol = n0 + j * 32 + l31;
      if (gcol < NN){
        #pragma unroll
        for (int reg = 0; reg < 16; ++reg){
          int grow = m0 + w * 64 + i * 32 + (reg & 3) + 8 * (reg >> 2) + 4 * lhi;
          float v = (acc[i][j][reg] + rowAdd[grow]) * alpha;
          C[(size_t)grow * NN + gcol] = v;
        }
      }
    }
  }
}

extern "C" void kernel_launch(void* const* d_in, const int* in_sizes, int n_in,
                              void* d_out, int out_size, void* d_ws, size_t ws_size,
                              hipStream_t stream){
  (void)in_sizes; (void)n_in; (void)out_size; (void)ws_size;
  const float* m    = (const float*)d_in[0];   // [512][2048]
  const float* tpl  = (const float*)d_in[1];   // [50000][2048]
  const float* Wmol = (const float*)d_in[2];   // [1024][2048]
  const float* bmol = (const float*)d_in[3];   // [1024]
  const float* Wtmp = (const float*)d_in[4];   // [1024][2048]
  const float* btmp = (const float*)d_in[5];   // [1024]
  float* out = (float*)d_out;                  // [512][50000]

  uint8_t* wp = (uint8_t*)d_ws;
  auto carve = [&](size_t bytes) -> void* {
    void* p = (void*)wp;
    wp += (bytes + 255) & ~(size_t)255;
    return p;
  };
  u16* m_hi   = (u16*)carve((size_t)BB_ * FP_ * 2);
  u16* m_lo   = (u16*)carve((size_t)BB_ * FP_ * 2);
  u16* wm_hi  = (u16*)carve((size_t)AD_ * FP_ * 2);
  u16* wm_lo  = (u16*)carve((size_t)AD_ * FP_ * 2);
  u16* wtT_hi = (u16*)carve((size_t)FP_ * AD_ * 2);
  u16* wtT_lo = (u16*)carve((size_t)FP_ * AD_ * 2);
  float* Xi   = (float*)carve((size_t)BB_ * AD_ * 4);
  u16* Xi_hi  = (u16*)carve((size_t)BB_ * AD_ * 2);
  u16* Xi_lo  = (u16*)carve((size_t)BB_ * AD_ * 2);
  u16* Y_hi   = (u16*)carve((size_t)BB_ * FP_ * 2);   // fp16 bits
  u16* Y_lo   = (u16*)carve((size_t)BB_ * FP_ * 2);   // fp16 bits (unused by big gemm)
  float* cvec = (float*)carve((size_t)BB_ * 4);

  // 1) split inputs to bf16 hi/lo (W_temp also transposed to [FP][A])
  conv_hilo_k<<<(BB_ * FP_ / 4 + 255) / 256, 256, 0, stream>>>(m, m_hi, m_lo, BB_ * FP_);
  conv_hilo_k<<<(AD_ * FP_ / 4 + 255) / 256, 256, 0, stream>>>(Wmol, wm_hi, wm_lo, AD_ * FP_);
  conv_hilo_T_k<<<dim3(FP_ / 32, AD_ / 32), dim3(32, 8), 0, stream>>>(Wtmp, wtT_hi, wtT_lo, AD_, FP_);

  // 2) Xi = m @ W_mol^T + b_mol   [512 x 1024], K=2048  (fp32 + bf16 hi/lo out)
  gemm_hilo<64, 64, 2, 2, 1><<<dim3(BB_ / 64, AD_ / 64), 256, 0, stream>>>(
      m_hi, m_lo, wm_hi, wm_lo, BB_, AD_, FP_,
      Xi, Xi_hi, Xi_lo, bmol);

  // 3) c[b] = Xi[b,:] . b_temp
  dot_rows_k<<<BB_ / 4, 256, 0, stream>>>(Xi, btmp, cvec, AD_);

  // 4) Y = Xi @ W_temp   [512 x 2048], K=1024  -> fp16 hi/lo (big gemm uses hi only)
  gemm_hilo<64, 64, 2, 2, 2><<<dim3(BB_ / 64, FP_ / 64), 256, 0, stream>>>(
      Xi_hi, Xi_lo, wtT_hi, wtT_lo, BB_, FP_, AD_,
      nullptr, Y_hi, Y_lo, nullptr);

  // 5) out = BETA * (Y @ templates^T + c)   [512 x 50000], K=2048
  //    1568 blocks = 8 XCD x 49 strips x 4 M-tiles; 4 masked. 4 blocks/CU.
  gemm_big<<<1568, 128, 0, stream>>>(Y_hi, tpl, out, cvec, BETA_);
}